// Round 1
// baseline (76.088 us; speedup 1.0000x reference)
//
#include <hip/hip_runtime.h>

// Ball query via 5x5x5 uniform grid + counting sort + per-wave hit bitmap.
// B=4, N1=2048 queries, N2=8192 keys, K=64, r=0.1 (cell = 0.2 = 2r, so a
// query ball overlaps at most a 2x2x2 octant of cells).
//
// TWO kernel nodes (was 3: hist -> scatter -> query). The hist/scatter pair
// communicated per-sub-block histograms through global memory, costing a
// dispatch + drain + a hists[128][125] round-trip. Now each build block is
// self-sufficient: it re-reads its entire batch's keys (96 KB, L2-hot;
// 12 MB total extra reads ~= 2 us of BW) and accumulates BOTH the per-cell
// batch totals (h_tot) and the prefix counts of sub-blocks before it (h_pre)
// in LDS. Note j < s*256  <=>  i < s for j = i*256+t, so the prefix
// condition is wave-uniform (no divergence). Per-(sub,cell) output ranges
// stay disjoint => race-free deterministic scatter, no global atomics.
//
//   1. build_kernel : 128 blocks x 256 thr. hist + scan + scatter fused.
//   2. ballquery_grid_kernel : one wave per query; scans <=4 contiguous
//      (x,y)-column z-runs, sets bits in an 8192-bit LDS bitmap keyed by
//      ORIGINAL key index, then extracts the first K set bits in order
//      (exact key-order output, even when >K hits). Unchanged behavior.

constexpr int   K    = 64;
constexpr float R2   = 0.01f;   // 0.1^2
constexpr int   B    = 4;
constexpr int   N1   = 2048;
constexpr int   N2   = 8192;
constexpr int   GC   = 5;                 // grid cells per dim
constexpr int   NCELL = GC * GC * GC;     // 125
constexpr float INVCELL = 5.0f;           // 1 / 0.2
constexpr int   SUBS_PER_B = 32;          // 256-key sub-blocks per batch
constexpr int   SUBS       = B * SUBS_PER_B;   // 128

// ---------------- workspace layout ----------------
// [0, 512KB) : sorted float4 [B*N2]
// then       : cell_start [B*(NCELL+1)] ints
constexpr size_t SORTED_BYTES = (size_t)B * N2 * 16;
constexpr size_t CS_BYTES     = (size_t)B * (NCELL + 1) * 4;
constexpr size_t WS_NEEDED    = SORTED_BYTES + CS_BYTES;

__device__ __forceinline__ int cell_of(float v) {
    int c = (int)(v * INVCELL);
    return c < 0 ? 0 : (c > GC - 1 ? GC - 1 : c);
}

// ---------------- pass 1: fused hist + scan + scatter ----------------
__global__ __launch_bounds__(256) void build_kernel(
    const float* __restrict__ key,       // [B*N2, 3]
    int* __restrict__ cell_start,        // [B, NCELL+1]
    float4* __restrict__ sorted)         // [B*N2]
{
    __shared__ int h_tot[NCELL];         // batch per-cell totals
    __shared__ int h_pre[NCELL];         // per-cell counts of subs before mine
    __shared__ int sbuf[128];            // scan buffer
    __shared__ int cursor[NCELL];        // block-local scatter cursors

    const int k = blockIdx.x;            // sub-block id 0..127
    const int b = k >> 5;                // batch
    const int s = k & 31;                // sub index within batch
    const int t = threadIdx.x;

    if (t < NCELL) { h_tot[t] = 0; h_pre[t] = 0; }
    __syncthreads();

    // Scan the whole batch's keys once (32 x 256). Condition i<s is
    // wave-uniform; my own key shows up at i==s (also uniform).
    const float* kb = key + (size_t)b * N2 * 3;
    float mx = 0.f, my = 0.f, mz = 0.f;
    int mycell = 0;
    for (int i = 0; i < SUBS_PER_B; ++i) {
        const int j = i * 256 + t;
        const float x = kb[j * 3 + 0];
        const float y = kb[j * 3 + 1];
        const float z = kb[j * 3 + 2];
        const int c = (cell_of(x) * GC + cell_of(y)) * GC + cell_of(z);
        atomicAdd(&h_tot[c], 1);
        if (i < s) atomicAdd(&h_pre[c], 1);
        if (i == s) { mx = x; my = y; mz = z; mycell = c; }
    }
    __syncthreads();

    // Inclusive Hillis-Steele scan of per-cell totals (threads 0-127,
    // barriers unconditional for the whole block).
    const int total = (t < NCELL) ? h_tot[t] : 0;
    if (t < 128) sbuf[t] = total;
    __syncthreads();
    for (int off = 1; off < 128; off <<= 1) {
        int v = 0;
        if (t < 128 && t >= off) v = sbuf[t - off];
        __syncthreads();
        if (t < 128) sbuf[t] += v;
        __syncthreads();
    }
    if (t < NCELL) {
        const int excl = sbuf[t] - total;          // exclusive cell start
        cursor[t] = excl + h_pre[t];               // my sub-block's base
        if (s == 0) {                              // one writer per batch
            cell_start[b * (NCELL + 1) + t + 1] = sbuf[t];
            if (t == 0) cell_start[b * (NCELL + 1)] = 0;
        }
    }
    __syncthreads();

    // Scatter my 256 keys. Within-cell order arbitrary (bitmap restores it).
    const int pos = atomicAdd(&cursor[mycell], 1); // LDS, block-local
    float4 v;
    v.x = mx; v.y = my; v.z = mz; v.w = __int_as_float(s * 256 + t);
    sorted[(size_t)b * N2 + pos] = v;
}

// ---------------- per-query grid scan ----------------
__global__ __launch_bounds__(256) void ballquery_grid_kernel(
    const float* __restrict__ query,        // [B*N1, 3]
    const float4* __restrict__ sorted,      // [B*N2] grouped by cell
    const int* __restrict__ cell_start,     // [B, 126]
    int* __restrict__ out)                  // [B*N1, K]
{
    __shared__ unsigned int bm[4 * 256];    // 4 waves x 8192-bit bitmap

    const int lane = threadIdx.x & 63;
    const int wv   = threadIdx.x >> 6;
    const int q    = blockIdx.x * 4 + wv;   // 0 .. B*N1-1
    const int b    = q >> 11;

    const float qx = query[q * 3 + 0];
    const float qy = query[q * 3 + 1];
    const float qz = query[q * 3 + 2];

    // Octant of cells the ball can touch (cell = 2r, so +/-1 on the near side).
    const float ux = qx * INVCELL, uy = qy * INVCELL, uz = qz * INVCELL;
    const int cx = cell_of(qx), cy = cell_of(qy), cz = cell_of(qz);
    const int nx = (ux - cx < 0.5f) ? cx - 1 : cx + 1;
    const int ny = (uy - cy < 0.5f) ? cy - 1 : cy + 1;
    const int nz = (uz - cz < 0.5f) ? cz - 1 : cz + 1;
    const int xlo = max(0, min(cx, nx)), xhi = min(GC - 1, max(cx, nx));
    const int ylo = max(0, min(cy, ny)), yhi = min(GC - 1, max(cy, ny));
    const int zlo = max(0, min(cz, nz)), zhi = min(GC - 1, max(cz, nz));

    // Bitmap is strictly wave-private: no fences/barriers needed, the
    // compiler's LDS dependence tracking orders write->atomic->read.
    unsigned int* wbm = bm + wv * 256;
    uint4 zz; zz.x = zz.y = zz.z = zz.w = 0u;
    ((uint4*)wbm)[lane] = zz;               // clear bitmap (ds_write_b128)

    const int*    cs = cell_start + b * (NCELL + 1);
    const float4* sb = sorted + (size_t)b * N2;

    for (int xx = xlo; xx <= xhi; ++xx) {
        for (int yy = ylo; yy <= yhi; ++yy) {
            const int colz = (xx * GC + yy) * GC;
            const int s = cs[colz + zlo];
            const int e = cs[colz + zhi + 1];          // z-cells are contiguous
            for (int t0 = s; t0 < e; t0 += 64) {
                const int i = t0 + lane;
                const float4 kv = sb[min(i, e - 1)];
                const float dx = kv.x - qx;
                const float dy = kv.y - qy;
                const float dz = kv.z - qz;
                const bool within = (i < e) && (dx * dx + dy * dy + dz * dz < R2);
                if (within) {
                    const int id = __float_as_int(kv.w);
                    atomicOr(&wbm[id >> 5], 1u << (id & 31));
                }
            }
        }
    }

    // ---- extraction: lane owns original-index range [128*lane, 128*lane+128)
    const uint4 w = ((const uint4*)wbm)[lane];
    const int c = __popc(w.x) + __popc(w.y) + __popc(w.z) + __popc(w.w);

    // inclusive wave prefix sum of c
    int x = c;
    #pragma unroll
    for (int off = 1; off < 64; off <<= 1) {
        int y = __shfl_up(x, off);
        if (lane >= off) x += y;
    }
    const int base = x - c;
    const int cnt  = __shfl(x, 63);

    // first set bit overall (0 if none)
    int fs;
    if      (w.x) fs = __builtin_ctz(w.x);
    else if (w.y) fs = 32 + __builtin_ctz(w.y);
    else if (w.z) fs = 64 + __builtin_ctz(w.z);
    else if (w.w) fs = 96 + __builtin_ctz(w.w);
    else          fs = 0;
    int myfirst = c ? (lane << 7) + fs : 0x7fffffff;
    #pragma unroll
    for (int off = 32; off; off >>= 1)
        myfirst = min(myfirst, __shfl_xor(myfirst, off));
    const int firstIdx = (cnt == 0) ? 0 : myfirst;

    // emit set bits in order
    int* op = out + q * K;
    int slot = base;
    unsigned int wr[4] = {w.x, w.y, w.z, w.w};
    #pragma unroll
    for (int r = 0; r < 4; ++r) {
        unsigned int m = wr[r];
        const int bb = (lane << 7) + (r << 5);
        while (m) {
            const int bp = __builtin_ctz(m);
            m &= m - 1;
            if (slot < K) op[slot] = bb + bp;
            ++slot;
        }
    }

    // pad remaining slots with firstIdx
    const int kpad = cnt < K ? cnt : K;
    const int s2 = kpad + lane;
    if (s2 < K) op[s2] = firstIdx;
}

// ---------------- fallback (ws too small): brute force ----------------
__global__ __launch_bounds__(256) void ballquery_bruteforce_kernel(
    const float* __restrict__ query, const float* __restrict__ key,
    int* __restrict__ out)
{
    const int lane = threadIdx.x & 63;
    const int q = blockIdx.x * 4 + (threadIdx.x >> 6);
    const int b = q >> 11;
    const float qx = query[q * 3], qy = query[q * 3 + 1], qz = query[q * 3 + 2];
    const float* kb = key + (size_t)b * N2 * 3;
    int* op = out + (size_t)q * K;
    int count = 0, first = 0;
    bool have_first = false;
    const unsigned long long lane_mask_lt = (lane == 0) ? 0ull : (~0ull >> (64 - lane));
    for (int c = 0; c < N2 / 64; ++c) {
        if (count >= K) break;
        const int j = (c << 6) + lane;
        const float* kp = kb + j * 3;
        const float dx = kp[0] - qx, dy = kp[1] - qy, dz = kp[2] - qz;
        const bool within = dx * dx + dy * dy + dz * dz < R2;
        const unsigned long long mask = __ballot(within);
        if (mask) {
            if (!have_first) { first = (c << 6) + __builtin_ctzll(mask); have_first = true; }
            if (within) {
                const int slot = count + __popcll(mask & lane_mask_lt);
                if (slot < K) op[slot] = j;
            }
            count += __popcll(mask);
        }
    }
    const int cnt = count < K ? count : K;
    if (cnt + lane < K) op[cnt + lane] = first;
}

extern "C" void kernel_launch(void* const* d_in, const int* in_sizes, int n_in,
                              void* d_out, int out_size, void* d_ws, size_t ws_size,
                              hipStream_t stream) {
    const float* query = (const float*)d_in[0];   // B*N1*3 floats
    const float* key   = (const float*)d_in[1];   // B*N2*3 floats
    int* out = (int*)d_out;                       // B*N1*K int32

    if (ws_size < WS_NEEDED) {
        ballquery_bruteforce_kernel<<<(B * N1) / 4, 256, 0, stream>>>(query, key, out);
        return;
    }

    float4* sorted     = (float4*)d_ws;
    int*    cell_start = (int*)((char*)d_ws + SORTED_BYTES);

    build_kernel<<<SUBS, 256, 0, stream>>>(key, cell_start, sorted);
    ballquery_grid_kernel<<<(B * N1) / 4, 256, 0, stream>>>(query, sorted, cell_start, out);
}